// Round 7
// baseline (20.182 us; speedup 1.0000x reference)
//
#include <hip/hip_runtime.h>

#define HW_BIG   1e10f
#define LOSS_EPS 1e-8f

typedef unsigned long long u64;

// ---------------------------------------------------------------------------
// distance (in pixels) to nearest set bit in a 256-bit row mask rm[4] from
// position y. Returns 32768 if the row is empty. Exact.
// ---------------------------------------------------------------------------
__device__ __forceinline__ int row_nearest(const u64* rm, int y) {
    const int yw = y >> 6, yb = y & 63;
    int dd = 32768;
    u64 w = rm[yw] & (~0ULL >> (63 - yb));
    int j = yw;
    while (w == 0 && j > 0) w = rm[--j];
    if (w) dd = y - (j * 64 + 63 - __builtin_clzll(w));
    u64 w2 = rm[yw] & (~0ULL << yb);
    int j2 = yw;
    while (w2 == 0 && j2 < 3) w2 = rm[++j2];
    if (w2) { int du = (j2 * 64 + __builtin_ctzll(w2)) - y; dd = min(dd, du); }
    return dd;
}

// ---------------------------------------------------------------------------
// Kernel 1: block = (img, 4-row group), 1024 threads. One load per pixel ->
// ballot row bitmasks -> word-parallel 4-neighbor boundary (zero-padded
// borders). Outputs row bitmasks only. Block 0 also zeroes out[0] for
// kernel 2's per-block atomicAdd (visible at kernel boundary).
// ---------------------------------------------------------------------------
__global__ void k_masks(const float* __restrict__ inp,
                        const float* __restrict__ tgt,
                        u64* __restrict__ rows_bib,
                        u64* __restrict__ rows_blb,
                        u64* __restrict__ rows_ml,
                        float* __restrict__ out) {
    __shared__ u64 V[6][4];     // rows r0..r0+3 (0..3), up-halo (4), down-halo (5)
    __shared__ u64 T[6][4];
    const int tid = threadIdx.x;
    const int img = blockIdx.x >> 6;
    const int r0  = (blockIdx.x & 63) * 4;
    const int r   = tid >> 8;          // 0..3
    const int y   = tid & 255;
    const int w   = y >> 6;            // word index (uniform per wave)
    const float* ip = inp + (size_t)img * 65536;
    const float* tp = tgt + (size_t)img * 65536;

    if (blockIdx.x == 0 && tid == 0) out[0] = 0.0f;

    const int x = r0 + r;
    bool vb = ip[x * 256 + y] > 0.0f;        // sigmoid(v)>0.5  <=>  v>0
    bool tb = tp[x * 256 + y] > 0.5f;
    u64 bv = __ballot(vb);
    u64 bt = __ballot(tb);
    if ((y & 63) == 0) { V[r][w] = bv; T[r][w] = bt; }

    if (tid < 256) {                          // up halo (border = background)
        const int xh = r0 - 1;
        bool hv = (xh >= 0) && (ip[xh * 256 + y] > 0.0f);
        bool ht = (xh >= 0) && (tp[xh * 256 + y] > 0.5f);
        u64 a = __ballot(hv), b = __ballot(ht);
        if ((y & 63) == 0) { V[4][w] = a; T[4][w] = b; }
    } else if (tid < 512) {                   // down halo
        const int xh = r0 + 4;
        bool hv = (xh < 256) && (ip[xh * 256 + y] > 0.0f);
        bool ht = (xh < 256) && (tp[xh * 256 + y] > 0.5f);
        u64 a = __ballot(hv), b = __ballot(ht);
        if ((y & 63) == 0) { V[5][w] = a; T[5][w] = b; }
    }
    __syncthreads();

    if (tid < 32) {
        const int rr = (tid >> 2) & 3;
        const int j  = tid & 3;
        const bool isT = tid >= 16;
        const u64 (*M)[4] = isT ? T : V;
        u64 own = M[rr][j];
        u64 up  = (rr == 0) ? M[4][j] : M[rr - 1][j];
        u64 dn  = (rr == 3) ? M[5][j] : M[rr + 1][j];
        u64 lf  = (own << 1) | ((j > 0) ? (M[rr][j - 1] >> 63) : 0ULL);
        u64 rt  = (own >> 1) | ((j < 3) ? (M[rr][j + 1] << 63) : 0ULL);
        u64 bnd = own & ~(up & dn & lf & rt);
        const size_t o = ((size_t)img * 256 + (r0 + rr)) * 4 + j;
        if (!isT) rows_bib[o] = bnd;
        else      { rows_blb[o] = bnd; rows_ml[o] = own; }
    }
}

// ---------------------------------------------------------------------------
// Kernel 2 (DT + loss + per-block atomic): block = (img, 4 output y-rows),
// 1024 threads = (x = tid>>2, yr = tid&3). Whole-image masks in LDS; each
// thread computes G[x][yr] = (nearest boundary bit in row x from y)^2 in
// pass-B orientation, then the exact early-exit outward scan over x', fused
// weight + focal BCE, deterministic 16-wave block reduction, and ONE
// atomicAdd(out) per block (no fences - G12 pattern).
// Thread remap gives 16B/cacheline inp reads and conflict-free G (idx = tid).
// ---------------------------------------------------------------------------
__global__ void k_dt_loss(const float* __restrict__ inp,
                          const u64* __restrict__ rows_bib,
                          const u64* __restrict__ rows_blb,
                          const u64* __restrict__ rows_ml,
                          float* __restrict__ out,
                          float inv_count) {
    __shared__ u64 Mib[1024];      // [row x][word] image-boundary bits
    __shared__ u64 Mlb[1024];      // label-boundary bits
    __shared__ u64 Mml[1024];      // label mask bits
    __shared__ float G1[256][4];   // g indexed [x'][yr]  (word idx = tid)
    __shared__ float G2[256][4];
    __shared__ float wsum[16];
    const int tid = threadIdx.x;
    const int img = blockIdx.x >> 6;
    const int y0  = (blockIdx.x & 63) * 4;
    const int x   = tid >> 2;           // 0..255
    const int yr  = tid & 3;            // 0..3
    const int y   = y0 + yr;
    const int yw  = y >> 6, yb = y & 63;

    const size_t mbase = (size_t)img * 1024;
    Mib[tid] = rows_bib[mbase + tid];
    Mlb[tid] = rows_blb[mbase + tid];
    Mml[tid] = rows_ml[mbase + tid];
    // v at (x, y): 4 consecutive lanes read 16 contiguous bytes
    const float v = inp[((size_t)img * 256 + x) * 256 + y];
    __syncthreads();

    const bool fib = (Mib[x * 4 + yw] >> yb) & 1;
    const bool flb = (Mlb[x * 4 + yw] >> yb) & 1;
    const float t  = ((Mml[x * 4 + yw] >> yb) & 1) ? 1.0f : 0.0f;

    const int d1 = row_nearest(&Mib[x * 4], y);
    const int d2 = row_nearest(&Mlb[x * 4], y);
    G1[x][yr] = (d1 > 255) ? HW_BIG : (float)(d1 * d1);
    G2[x][yr] = (d2 > 255) ? HW_BIG : (float)(d2 * d2);
    __syncthreads();

    // exact early-exit outward scan over x' = x -+ d. Lanes that don't
    // consume a distance (m1 used only where flb, m2 where fib) init to 0
    // so they never prolong the scan.
    float m1 = flb ? G1[x][yr] : 0.0f;
    float m2 = fib ? G2[x][yr] : 0.0f;
    for (int d = 1; d < 256; ++d) {
        const float fd2 = (float)(d * d);          // exact integer in f32
        if (fd2 >= m1 && fd2 >= m2) break;
        const int xl = x - d;
        if (xl >= 0)  { m1 = fminf(m1, G1[xl][yr] + fd2); m2 = fminf(m2, G2[xl][yr] + fd2); }
        const int xr = x + d;
        if (xr < 256) { m1 = fminf(m1, G1[xr][yr] + fd2); m2 = fminf(m2, G2[xr][yr] + fd2); }
    }

    const float p = 1.0f / (1.0f + expf(-v));
    float wgt = 1.0f;
    if (flb) wgt += expf(-sqrtf(m1));   // THETA=1, SIGMA=1
    if (fib) wgt += expf(-sqrtf(m2));

    // GAMMA = 1
    float loss = wgt * (-(1.0f - p) * t * logf(p + LOSS_EPS)
                        - p * (1.0f - t) * logf(1.0f - p + LOSS_EPS));

    // deterministic block reduction: wave shfl tree + 16 wave partials
    float s = loss;
#pragma unroll
    for (int off = 32; off > 0; off >>= 1) s += __shfl_down(s, off, 64);
    if ((tid & 63) == 0) wsum[tid >> 6] = s;
    __syncthreads();
    if (tid == 0) {
        float bs = 0.0f;
#pragma unroll
        for (int i = 0; i < 16; ++i) bs += wsum[i];
        atomicAdd(out, bs * inv_count);   // one device-scope atomic per block
    }
}

// ---------------------------------------------------------------------------
extern "C" void kernel_launch(void* const* d_in, const int* in_sizes, int n_in,
                              void* d_out, int out_size, void* d_ws, size_t ws_size,
                              hipStream_t stream) {
    const float* inp = (const float*)d_in[0];
    const float* tgt = (const float*)d_in[1];
    float* out = (float*)d_out;

    const int total = in_sizes[0];          // B*256*256
    const int nimg  = total / 65536;        // B = 8
    const int nblk  = nimg * 64;            // 512 blocks of 1024 threads

    char* ws = (char*)d_ws;
    u64* rows_bib = (u64*)ws;                       // nimg*1024 u64 each
    u64* rows_blb = rows_bib + (size_t)nimg * 1024;
    u64* rows_ml  = rows_blb + (size_t)nimg * 1024;

    k_masks  <<<nblk, 1024, 0, stream>>>(inp, tgt, rows_bib, rows_blb, rows_ml, out);
    k_dt_loss<<<nblk, 1024, 0, stream>>>(inp, rows_bib, rows_blb, rows_ml, out,
                                         1.0f / (float)total);
}

// Round 8
// 17.230 us; speedup vs baseline: 1.1713x; 1.1713x over previous
//
#include <hip/hip_runtime.h>

#define HW_BIG   1e10f
#define LOSS_EPS 1e-8f

typedef unsigned long long u64;

// ---------------------------------------------------------------------------
// distance (in pixels) to nearest set bit in a 256-bit row mask rm[4] from
// position y. Returns 32768 if the row is empty. Exact.
// ---------------------------------------------------------------------------
__device__ __forceinline__ int row_nearest(const u64* rm, int y) {
    const int yw = y >> 6, yb = y & 63;
    int dd = 32768;
    u64 w = rm[yw] & (~0ULL >> (63 - yb));
    int j = yw;
    while (w == 0 && j > 0) w = rm[--j];
    if (w) dd = y - (j * 64 + 63 - __builtin_clzll(w));
    u64 w2 = rm[yw] & (~0ULL << yb);
    int j2 = yw;
    while (w2 == 0 && j2 < 3) w2 = rm[++j2];
    if (w2) { int du = (j2 * 64 + __builtin_ctzll(w2)) - y; dd = min(dd, du); }
    return dd;
}

// ---------------------------------------------------------------------------
// Kernel 1: block = (img, 4-row group), 1024 threads. One load per pixel ->
// ballot row bitmasks -> word-parallel 4-neighbor boundary (zero-padded
// borders). Outputs row bitmasks only.
// ---------------------------------------------------------------------------
__global__ void k_masks(const float* __restrict__ inp,
                        const float* __restrict__ tgt,
                        u64* __restrict__ rows_bib,
                        u64* __restrict__ rows_blb,
                        u64* __restrict__ rows_ml) {
    __shared__ u64 V[6][4];     // rows r0..r0+3 (0..3), up-halo (4), down-halo (5)
    __shared__ u64 T[6][4];
    const int tid = threadIdx.x;
    const int img = blockIdx.x >> 6;
    const int r0  = (blockIdx.x & 63) * 4;
    const int r   = tid >> 8;          // 0..3
    const int y   = tid & 255;
    const int w   = y >> 6;            // word index (uniform per wave)
    const float* ip = inp + (size_t)img * 65536;
    const float* tp = tgt + (size_t)img * 65536;

    const int x = r0 + r;
    bool vb = ip[x * 256 + y] > 0.0f;        // sigmoid(v)>0.5  <=>  v>0
    bool tb = tp[x * 256 + y] > 0.5f;
    u64 bv = __ballot(vb);
    u64 bt = __ballot(tb);
    if ((y & 63) == 0) { V[r][w] = bv; T[r][w] = bt; }

    if (tid < 256) {                          // up halo (border = background)
        const int xh = r0 - 1;
        bool hv = (xh >= 0) && (ip[xh * 256 + y] > 0.0f);
        bool ht = (xh >= 0) && (tp[xh * 256 + y] > 0.5f);
        u64 a = __ballot(hv), b = __ballot(ht);
        if ((y & 63) == 0) { V[4][w] = a; T[4][w] = b; }
    } else if (tid < 512) {                   // down halo
        const int xh = r0 + 4;
        bool hv = (xh < 256) && (ip[xh * 256 + y] > 0.0f);
        bool ht = (xh < 256) && (tp[xh * 256 + y] > 0.5f);
        u64 a = __ballot(hv), b = __ballot(ht);
        if ((y & 63) == 0) { V[5][w] = a; T[5][w] = b; }
    }
    __syncthreads();

    if (tid < 32) {
        const int rr = (tid >> 2) & 3;
        const int j  = tid & 3;
        const bool isT = tid >= 16;
        const u64 (*M)[4] = isT ? T : V;
        u64 own = M[rr][j];
        u64 up  = (rr == 0) ? M[4][j] : M[rr - 1][j];
        u64 dn  = (rr == 3) ? M[5][j] : M[rr + 1][j];
        u64 lf  = (own << 1) | ((j > 0) ? (M[rr][j - 1] >> 63) : 0ULL);
        u64 rt  = (own >> 1) | ((j < 3) ? (M[rr][j + 1] << 63) : 0ULL);
        u64 bnd = own & ~(up & dn & lf & rt);
        const size_t o = ((size_t)img * 256 + (r0 + rr)) * 4 + j;
        if (!isT) rows_bib[o] = bnd;
        else      { rows_blb[o] = bnd; rows_ml[o] = own; }
    }
}

// ---------------------------------------------------------------------------
// Kernel 2 (DT + loss, 8 y-rows/block): block = (img, 8 output y-rows),
// 1024 threads = (x = tid>>2, yq = tid&3); each thread handles pixels
// (x, y0+yq) and (x, y0+yq+4). Whole-image masks staged once in LDS; per
// pixel G[x][yr] = (nearest boundary bit in row x from y)^2 in pass-B
// orientation, exact early-exit outward scan over x', fused weight +
// focal BCE (fast __expf/__logf), deterministic 16-wave block reduction.
// ---------------------------------------------------------------------------
__global__ void k_dt_loss(const float* __restrict__ inp,
                          const u64* __restrict__ rows_bib,
                          const u64* __restrict__ rows_blb,
                          const u64* __restrict__ rows_ml,
                          float* __restrict__ partials) {
    __shared__ u64 Mib[1024];      // [row x][word] image-boundary bits
    __shared__ u64 Mlb[1024];      // label-boundary bits
    __shared__ u64 Mml[1024];      // label mask bits
    __shared__ float G1[256][8];   // g indexed [x'][yr]
    __shared__ float G2[256][8];
    __shared__ float wsum[16];
    const int tid = threadIdx.x;
    const int img = blockIdx.x >> 5;
    const int y0  = (blockIdx.x & 31) * 8;
    const int x   = tid >> 2;           // 0..255
    const int yq  = tid & 3;            // 0..3
    const int ya  = y0 + yq;
    const int yb  = ya + 4;

    const size_t mbase = (size_t)img * 1024;
    Mib[tid] = rows_bib[mbase + tid];
    Mlb[tid] = rows_blb[mbase + tid];
    Mml[tid] = rows_ml[mbase + tid];
    // 4 consecutive lanes read 16 contiguous bytes (x uniform per lane quad)
    const float va = inp[((size_t)img * 256 + x) * 256 + ya];
    const float vb = inp[((size_t)img * 256 + x) * 256 + yb];
    __syncthreads();

    const int ywa = ya >> 6, yba = ya & 63;
    const int ywb = yb >> 6, ybb = yb & 63;
    const bool fibA = (Mib[x * 4 + ywa] >> yba) & 1;
    const bool flbA = (Mlb[x * 4 + ywa] >> yba) & 1;
    const float tA  = ((Mml[x * 4 + ywa] >> yba) & 1) ? 1.0f : 0.0f;
    const bool fibB = (Mib[x * 4 + ywb] >> ybb) & 1;
    const bool flbB = (Mlb[x * 4 + ywb] >> ybb) & 1;
    const float tB  = ((Mml[x * 4 + ywb] >> ybb) & 1) ? 1.0f : 0.0f;

    {
        const int d1a = row_nearest(&Mib[x * 4], ya);
        const int d2a = row_nearest(&Mlb[x * 4], ya);
        const int d1b = row_nearest(&Mib[x * 4], yb);
        const int d2b = row_nearest(&Mlb[x * 4], yb);
        G1[x][yq]     = (d1a > 255) ? HW_BIG : (float)(d1a * d1a);
        G2[x][yq]     = (d2a > 255) ? HW_BIG : (float)(d2a * d2a);
        G1[x][yq + 4] = (d1b > 255) ? HW_BIG : (float)(d1b * d1b);
        G2[x][yq + 4] = (d2b > 255) ? HW_BIG : (float)(d2b * d2b);
    }
    __syncthreads();

    // exact early-exit outward scans over x' = x -+ d (per pixel). Lanes that
    // don't consume a distance init to 0 so they never prolong the scan.
    float m1a = flbA ? G1[x][yq] : 0.0f;
    float m2a = fibA ? G2[x][yq] : 0.0f;
    for (int d = 1; d < 256; ++d) {
        const float fd2 = (float)(d * d);          // exact integer in f32
        if (fd2 >= m1a && fd2 >= m2a) break;
        const int xl = x - d;
        if (xl >= 0)  { m1a = fminf(m1a, G1[xl][yq] + fd2); m2a = fminf(m2a, G2[xl][yq] + fd2); }
        const int xr = x + d;
        if (xr < 256) { m1a = fminf(m1a, G1[xr][yq] + fd2); m2a = fminf(m2a, G2[xr][yq] + fd2); }
    }
    float m1b = flbB ? G1[x][yq + 4] : 0.0f;
    float m2b = fibB ? G2[x][yq + 4] : 0.0f;
    for (int d = 1; d < 256; ++d) {
        const float fd2 = (float)(d * d);
        if (fd2 >= m1b && fd2 >= m2b) break;
        const int xl = x - d;
        if (xl >= 0)  { m1b = fminf(m1b, G1[xl][yq + 4] + fd2); m2b = fminf(m2b, G2[xl][yq + 4] + fd2); }
        const int xr = x + d;
        if (xr < 256) { m1b = fminf(m1b, G1[xr][yq + 4] + fd2); m2b = fminf(m2b, G2[xr][yq + 4] + fd2); }
    }

    // fused weight + focal BCE (GAMMA=1, THETA=1, SIGMA=1), fast intrinsics
    const float pa = 1.0f / (1.0f + __expf(-va));
    float wA = 1.0f;
    if (flbA) wA += __expf(-sqrtf(m1a));
    if (fibA) wA += __expf(-sqrtf(m2a));
    float lossA = wA * (-(1.0f - pa) * tA * __logf(pa + LOSS_EPS)
                        - pa * (1.0f - tA) * __logf(1.0f - pa + LOSS_EPS));

    const float pb = 1.0f / (1.0f + __expf(-vb));
    float wB = 1.0f;
    if (flbB) wB += __expf(-sqrtf(m1b));
    if (fibB) wB += __expf(-sqrtf(m2b));
    float lossB = wB * (-(1.0f - pb) * tB * __logf(pb + LOSS_EPS)
                        - pb * (1.0f - tB) * __logf(1.0f - pb + LOSS_EPS));

    // deterministic block reduction: wave shfl tree + 16 wave partials
    float s = lossA + lossB;
#pragma unroll
    for (int off = 32; off > 0; off >>= 1) s += __shfl_down(s, off, 64);
    if ((tid & 63) == 0) wsum[tid >> 6] = s;
    __syncthreads();
    if (tid == 0) {
        float bs = 0.0f;
#pragma unroll
        for (int i = 0; i < 16; ++i) bs += wsum[i];
        partials[blockIdx.x] = bs;
    }
}

// ---------------------------------------------------------------------------
// Kernel 3: reduce partials -> mean (single block, fixed order, double accum)
// ---------------------------------------------------------------------------
__global__ void k_reduce(const float* __restrict__ partials, int n,
                         float* __restrict__ out, double inv_count) {
    __shared__ double sw[4];
    const int tid = threadIdx.x;
    double s = 0.0;
    for (int i = tid; i < n; i += 256) s += (double)partials[i];
#pragma unroll
    for (int off = 32; off > 0; off >>= 1) s += __shfl_down(s, off, 64);
    const int lane = tid & 63, wv = tid >> 6;
    if (lane == 0) sw[wv] = s;
    __syncthreads();
    if (tid == 0) out[0] = (float)(((sw[0] + sw[1]) + (sw[2] + sw[3])) * inv_count);
}

// ---------------------------------------------------------------------------
extern "C" void kernel_launch(void* const* d_in, const int* in_sizes, int n_in,
                              void* d_out, int out_size, void* d_ws, size_t ws_size,
                              hipStream_t stream) {
    const float* inp = (const float*)d_in[0];
    const float* tgt = (const float*)d_in[1];
    float* out = (float*)d_out;

    const int total = in_sizes[0];          // B*256*256
    const int nimg  = total / 65536;        // B = 8
    const int nblk1 = nimg * 64;            // 512 blocks (masks)
    const int nblk2 = nimg * 32;            // 256 blocks (DT+loss, 8 rows each)

    char* ws = (char*)d_ws;
    u64*   rows_bib = (u64*)ws;                       // nimg*1024 u64 each
    u64*   rows_blb = rows_bib + (size_t)nimg * 1024;
    u64*   rows_ml  = rows_blb + (size_t)nimg * 1024;
    float* parts    = (float*)(rows_ml + (size_t)nimg * 1024);

    k_masks  <<<nblk1, 1024, 0, stream>>>(inp, tgt, rows_bib, rows_blb, rows_ml);
    k_dt_loss<<<nblk2, 1024, 0, stream>>>(inp, rows_bib, rows_blb, rows_ml, parts);
    k_reduce <<<1,     256,  0, stream>>>(parts, nblk2, out, 1.0 / (double)total);
}